// Round 1
// baseline (144.540 us; speedup 1.0000x reference)
//
#include <hip/hip_runtime.h>

typedef unsigned short u16;
typedef __attribute__((ext_vector_type(8))) short bf16x8;   // 8 bf16 = 4 VGPR
typedef __attribute__((ext_vector_type(4))) float f32x4;
typedef __attribute__((ext_vector_type(8))) unsigned short u16x8;

#define DEVI static __device__ __forceinline__

constexpr int Bb = 8, Nn = 2048, Dd = 256;

DEVI u16 f2bf(float f) {
    unsigned int u = __builtin_bit_cast(unsigned int, f);
    u = (u + 0x7fffu + ((u >> 16) & 1u)) >> 16;   // RNE
    return (u16)u;
}

// ---------------- prep: x -> bf16 copy + row sum-of-squares -----------------
__global__ void prep_x_kernel(const float* __restrict__ x, u16* __restrict__ xb,
                              float* __restrict__ sq) {
    int row = blockIdx.x;
    int l = threadIdx.x;             // 64
    const float4 v = *(const float4*)(x + (size_t)row * Dd + l * 4);
    float ss = v.x * v.x + v.y * v.y + v.z * v.z + v.w * v.w;
    ushort4 o;
    o.x = f2bf(v.x); o.y = f2bf(v.y); o.z = f2bf(v.z); o.w = f2bf(v.w);
    *(ushort4*)(xb + (size_t)row * Dd + l * 4) = o;
#pragma unroll
    for (int s = 1; s < 64; s <<= 1) ss += __shfl_xor(ss, s);
    if (l == 0) sq[row] = ss;
}

// ---------------- prep: W -> bf16 ------------------------------------------
__global__ void prep_w_kernel(const float* __restrict__ W, u16* __restrict__ Wb) {
    int i = (blockIdx.x * 256 + threadIdx.x) * 4;
    const float4 v = *(const float4*)(W + i);
    ushort4 o;
    o.x = f2bf(v.x); o.y = f2bf(v.y); o.z = f2bf(v.z); o.w = f2bf(v.w);
    *(ushort4*)(Wb + i) = o;
}

// ---------------- prep: transpose xb (B,N,D) -> xbt (B,D,N), bf16 ----------
__global__ void prep_t_kernel(const u16* __restrict__ xb, u16* __restrict__ xbt) {
    int nt = blockIdx.x, dt = blockIdx.y, b = blockIdx.z;
    int n0 = nt * 64, d0 = dt * 64;
    __shared__ __align__(16) u16 tile[64 * 64];   // row n stride 128B, col swizzled
    int t = threadIdx.x;
#pragma unroll
    for (int p = 0; p < 2; ++p) {
        int row = p * 32 + (t >> 3);
        int c8 = t & 7;
        uint4 v = *(const uint4*)(xb + ((size_t)(b * Nn + n0 + row)) * Dd + d0 + c8 * 8);
        *(uint4*)((char*)tile + row * 128 + ((c8 * 16) ^ ((row & 7) << 4))) = v;
    }
    __syncthreads();
#pragma unroll
    for (int p = 0; p < 2; ++p) {
        int d = p * 32 + (t >> 3);
        int nn = (t & 7) * 8;
        u16x8 vv;
#pragma unroll
        for (int e = 0; e < 8; ++e) {
            int row = nn + e;
            vv[e] = *(const u16*)((char*)tile + row * 128 + ((d * 2) ^ ((row & 7) << 4)));
        }
        *(u16x8*)(xbt + ((size_t)(b * Dd + d0 + d)) * Nn + n0 + nn) = vv;
    }
}

// ---------------- fused: S = Xn.Xm^T, P = mean_h exp(-dist/denom), O += P.Xm
__global__ __launch_bounds__(256, 2) void fused_adj_kernel(
    const u16* __restrict__ xb, const u16* __restrict__ xbt,
    const float* __restrict__ sq, const float* __restrict__ lsig,
    u16* __restrict__ out1) {
    int bid = blockIdx.x;
    int b = bid & 7;                 // XCD-locality: one batch per XCD (round-robin)
    int n0 = (bid >> 3) * 64;
    int tid = threadIdx.x;
    int w = tid >> 6, l = tid & 63;
    int lrow = l & 15, lhi = l >> 4;

    __shared__ __align__(16) u16 sXm[64 * 256];    // row-major, 512B rows, swizzled
    __shared__ __align__(16) u16 sXmt[256 * 64];   // d-major,   128B rows, swizzled
    __shared__ __align__(16) u16 sP[4][16 * 64];   // per-wave P, 128B rows, swizzled

    // per-head constants: exp(-d/denom_h) = exp2(d * nc_h)
    float nc[4];
#pragma unroll
    for (int h = 0; h < 4; ++h) {
        float denom = 2.f * expf(2.f * lsig[h]) + 1e-6f;
        nc[h] = -1.44269504f / denom;
    }
    bool uniform = (lsig[0] == lsig[1]) && (lsig[1] == lsig[2]) && (lsig[2] == lsig[3]);

    // Xn A-fragments held in registers for the whole block
    bf16x8 af[8];
    {
        const u16* xr = xb + ((size_t)(b * Nn + n0 + w * 16 + lrow)) * Dd;
#pragma unroll
        for (int kt = 0; kt < 8; ++kt) af[kt] = *(const bf16x8*)(xr + kt * 32 + lhi * 8);
    }
    float sqn[4];
#pragma unroll
    for (int r = 0; r < 4; ++r) sqn[r] = sq[b * Nn + n0 + w * 16 + lhi * 4 + r];

    f32x4 of[16];
#pragma unroll
    for (int dt = 0; dt < 16; ++dt) of[dt] = (f32x4){0.f, 0.f, 0.f, 0.f};

    for (int m0 = 0; m0 < Nn; m0 += 64) {
        __syncthreads();
        // stage Xm tile (64 x 256 bf16)
#pragma unroll
        for (int it = 0; it < 8; ++it) {
            int li = it * 256 + tid;
            int row = li >> 5, c16 = li & 31;
            uint4 v = *(const uint4*)(xb + ((size_t)(b * Nn + m0 + row)) * Dd + c16 * 8);
            *(uint4*)((char*)sXm + row * 512 + ((c16 * 16) ^ ((row & 7) << 4))) = v;
        }
        // stage Xm^T tile (256 x 64 bf16)
#pragma unroll
        for (int it = 0; it < 8; ++it) {
            int li = it * 256 + tid;
            int drow = li >> 3, c16 = li & 7;
            uint4 v = *(const uint4*)(xbt + ((size_t)(b * Dd + drow)) * Nn + m0 + c16 * 8);
            *(uint4*)((char*)sXmt + drow * 128 + ((c16 * 16) ^ ((drow & 7) << 4))) = v;
        }
        float sqm[4];
#pragma unroll
        for (int jt = 0; jt < 4; ++jt) sqm[jt] = sq[b * Nn + m0 + jt * 16 + lrow];
        __syncthreads();

        // S = Xn . Xm^T   (wave: 16 rows x 64 cols)
        f32x4 sf[4];
#pragma unroll
        for (int jt = 0; jt < 4; ++jt) sf[jt] = (f32x4){0.f, 0.f, 0.f, 0.f};
#pragma unroll
        for (int kt = 0; kt < 8; ++kt) {
#pragma unroll
            for (int jt = 0; jt < 4; ++jt) {
                int row = jt * 16 + lrow;
                bf16x8 bv = *(const bf16x8*)((char*)sXm + row * 512 +
                                             (((kt * 32 + lhi * 8) * 2) ^ ((row & 7) << 4)));
                sf[jt] = __builtin_amdgcn_mfma_f32_16x16x32_bf16(af[kt], bv, sf[jt], 0, 0, 0);
            }
        }

        // P = mean_h exp(-dist * inv_denom_h)  -> per-wave LDS (bf16)
#pragma unroll
        for (int jt = 0; jt < 4; ++jt) {
#pragma unroll
            for (int r = 0; r < 4; ++r) {
                float d = sqn[r] + sqm[jt] - 2.f * sf[jt][r];
                d = fmaxf(d, 0.f);
                float p = exp2f(d * nc[0]);
                if (!uniform)
                    p = 0.25f * (p + exp2f(d * nc[1]) + exp2f(d * nc[2]) + exp2f(d * nc[3]));
                int i = lhi * 4 + r;
                int j = jt * 16 + lrow;
                *(u16*)((char*)&sP[w][0] + i * 128 + ((j * 2) ^ ((i & 7) << 4))) = f2bf(p);
            }
        }

        // O += P . Xm   (same-wave LDS RAW on sP; compiler orders via lgkmcnt)
#pragma unroll
        for (int kt2 = 0; kt2 < 2; ++kt2) {
            bf16x8 pa = *(const bf16x8*)((char*)&sP[w][0] + lrow * 128 +
                                         (((kt2 * 32 + lhi * 8) * 2) ^ ((lrow & 7) << 4)));
#pragma unroll
            for (int dt = 0; dt < 16; ++dt) {
                int row = dt * 16 + lrow;
                bf16x8 bv = *(const bf16x8*)((char*)sXmt + row * 128 +
                                             (((kt2 * 32 + lhi * 8) * 2) ^ ((row & 7) << 4)));
                of[dt] = __builtin_amdgcn_mfma_f32_16x16x32_bf16(pa, bv, of[dt], 0, 0, 0);
            }
        }
    }

    // write O tile as bf16
#pragma unroll
    for (int dt = 0; dt < 16; ++dt) {
#pragma unroll
        for (int r = 0; r < 4; ++r) {
            size_t row = (size_t)(b * Nn + n0 + w * 16 + lhi * 4 + r);
            out1[row * Dd + dt * 16 + lrow] = f2bf(of[dt][r]);
        }
    }
}

// ---------------- projection (out1 @ W^T + b) + ELU + residual + LayerNorm --
__global__ __launch_bounds__(256, 2) void proj_ln_kernel(
    const u16* __restrict__ out1, const u16* __restrict__ Wb,
    const float* __restrict__ x, const float* __restrict__ bvec,
    const float* __restrict__ gamma, const float* __restrict__ beta,
    float* __restrict__ out) {
    int tid = threadIdx.x, w = tid >> 6, l = tid & 63;
    int lrow = l & 15, lhi = l >> 4;
    size_t row0 = (size_t)blockIdx.x * 64 + w * 16;

    f32x4 acc[16];
#pragma unroll
    for (int jt = 0; jt < 16; ++jt) acc[jt] = (f32x4){0.f, 0.f, 0.f, 0.f};

    for (int kc = 0; kc < 8; ++kc) {
        bf16x8 a = *(const bf16x8*)(out1 + (row0 + lrow) * Dd + kc * 32 + lhi * 8);
#pragma unroll
        for (int jt = 0; jt < 16; ++jt) {
            bf16x8 bv = *(const bf16x8*)(Wb + (size_t)(jt * 16 + lrow) * Dd + kc * 32 + lhi * 8);
            acc[jt] = __builtin_amdgcn_mfma_f32_16x16x32_bf16(a, bv, acc[jt], 0, 0, 0);
        }
    }

#pragma unroll
    for (int r = 0; r < 4; ++r) {
        size_t grow = row0 + lhi * 4 + r;
        float vbuf[16];
        float s1 = 0.f, s2 = 0.f;
#pragma unroll
        for (int jt = 0; jt < 16; ++jt) {
            int j = jt * 16 + lrow;
            float v = acc[jt][r] + bvec[j];
            float e = v > 0.f ? v : (exp2f(v * 1.44269504f) - 1.f);   // ELU
            float res = e + x[grow * Dd + j];
            vbuf[jt] = res;
            s1 += res;
            s2 += res * res;
        }
#pragma unroll
        for (int m = 1; m < 16; m <<= 1) {
            s1 += __shfl_xor(s1, m);
            s2 += __shfl_xor(s2, m);
        }
        float mean = s1 * (1.f / 256.f);
        float var = s2 * (1.f / 256.f) - mean * mean;
        float rstd = rsqrtf(var + 1e-5f);
#pragma unroll
        for (int jt = 0; jt < 16; ++jt) {
            int j = jt * 16 + lrow;
            out[grow * Dd + j] = (vbuf[jt] - mean) * rstd * gamma[j] + beta[j];
        }
    }
}

// ---------------------------------------------------------------------------
extern "C" void kernel_launch(void* const* d_in, const int* in_sizes, int n_in,
                              void* d_out, int out_size, void* d_ws, size_t ws_size,
                              hipStream_t stream) {
    const float* x = (const float*)d_in[0];
    const float* lsig = (const float*)d_in[1];
    const float* W = (const float*)d_in[2];
    const float* bvec = (const float*)d_in[3];
    const float* gamma = (const float*)d_in[4];
    const float* beta = (const float*)d_in[5];
    float* out = (float*)d_out;

    char* ws = (char*)d_ws;
    u16* xb = (u16*)ws;                                  // 8 MiB
    u16* xbt = (u16*)(ws + 8ull * 1024 * 1024);          // 8 MiB
    u16* o1 = (u16*)(ws + 16ull * 1024 * 1024);          // 8 MiB
    float* sq = (float*)(ws + 24ull * 1024 * 1024);      // 64 KiB
    u16* Wb = (u16*)(ws + 24ull * 1024 * 1024 + 65536);  // 128 KiB

    prep_x_kernel<<<dim3(Bb * Nn), dim3(64), 0, stream>>>(x, xb, sq);
    prep_w_kernel<<<dim3(64), dim3(256), 0, stream>>>(W, Wb);
    prep_t_kernel<<<dim3(Nn / 64, Dd / 64, Bb), dim3(256), 0, stream>>>(xb, xbt);
    fused_adj_kernel<<<dim3(256), dim3(256), 0, stream>>>(xb, xbt, sq, lsig, o1);
    proj_ln_kernel<<<dim3(Bb * Nn / 64), dim3(256), 0, stream>>>(o1, Wb, x, bvec, gamma, beta, out);
}

// Round 2
// 137.600 us; speedup vs baseline: 1.0504x; 1.0504x over previous
//
#include <hip/hip_runtime.h>

typedef unsigned short u16;
typedef __attribute__((ext_vector_type(8))) short bf16x8;   // 8 bf16 = 4 VGPR
typedef __attribute__((ext_vector_type(4))) float f32x4;
typedef __attribute__((ext_vector_type(8))) unsigned short u16x8;

#define DEVI static __device__ __forceinline__

constexpr int Bb = 8, Nn = 2048, Dd = 256;

DEVI u16 f2bf(float f) {
    unsigned int u = __builtin_bit_cast(unsigned int, f);
    u = (u + 0x7fffu + ((u >> 16) & 1u)) >> 16;   // RNE
    return (u16)u;
}

// ---------------- prep: x -> bf16 copy + row sum-of-squares -----------------
__global__ void prep_x_kernel(const float* __restrict__ x, u16* __restrict__ xb,
                              float* __restrict__ sq) {
    int row = blockIdx.x * 4 + (threadIdx.x >> 6);
    int l = threadIdx.x & 63;
    const float4 v = *(const float4*)(x + (size_t)row * Dd + l * 4);
    float ss = v.x * v.x + v.y * v.y + v.z * v.z + v.w * v.w;
    ushort4 o;
    o.x = f2bf(v.x); o.y = f2bf(v.y); o.z = f2bf(v.z); o.w = f2bf(v.w);
    *(ushort4*)(xb + (size_t)row * Dd + l * 4) = o;
#pragma unroll
    for (int s = 1; s < 64; s <<= 1) ss += __shfl_xor(ss, s);
    if (l == 0) sq[row] = ss;
}

// ---------------- prep: W -> bf16 ------------------------------------------
__global__ void prep_w_kernel(const float* __restrict__ W, u16* __restrict__ Wb) {
    int i = (blockIdx.x * 256 + threadIdx.x) * 4;
    const float4 v = *(const float4*)(W + i);
    ushort4 o;
    o.x = f2bf(v.x); o.y = f2bf(v.y); o.z = f2bf(v.z); o.w = f2bf(v.w);
    *(ushort4*)(Wb + i) = o;
}

// ---------------- prep: transpose xb (B,N,D) -> xbt (B,D,N), bf16 ----------
__global__ void prep_t_kernel(const u16* __restrict__ xb, u16* __restrict__ xbt) {
    int nt = blockIdx.x, dt = blockIdx.y, b = blockIdx.z;
    int n0 = nt * 64, d0 = dt * 64;
    __shared__ __align__(16) u16 tile[64 * 64];   // row n stride 128B, col swizzled
    int t = threadIdx.x;
#pragma unroll
    for (int p = 0; p < 2; ++p) {
        int row = p * 32 + (t >> 3);
        int c8 = t & 7;
        uint4 v = *(const uint4*)(xb + ((size_t)(b * Nn + n0 + row)) * Dd + d0 + c8 * 8);
        *(uint4*)((char*)tile + row * 128 + ((c8 * 16) ^ ((row & 7) << 4))) = v;
    }
    __syncthreads();
#pragma unroll
    for (int p = 0; p < 2; ++p) {
        int d = p * 32 + (t >> 3);
        int nn = (t & 7) * 8;
        u16x8 vv;
#pragma unroll
        for (int e = 0; e < 8; ++e) {
            int row = nn + e;
            vv[e] = *(const u16*)((char*)tile + row * 128 + ((d * 2) ^ ((row & 7) << 4)));
        }
        *(u16x8*)(xbt + ((size_t)(b * Dd + d0 + d)) * Nn + n0 + nn) = vv;
    }
}

// ---------------- fused: S = Xn.Xm^T, P = mean_h exp(-dist/denom), O += P.Xm
// 512 threads = 8 waves: group g = w>>2 handles m-tiles of parity g into its
// own LDS buffer set; cross-group accumulator reduce at the end.
__global__ __launch_bounds__(512, 1) void fused_adj_kernel(
    const u16* __restrict__ xb, const u16* __restrict__ xbt,
    const float* __restrict__ sq, const float* __restrict__ lsig,
    u16* __restrict__ out1) {
    int bid = blockIdx.x;
    int b = bid & 7;                 // XCD-locality: one batch per XCD (round-robin)
    int n0 = (bid >> 3) * 64;
    int tid = threadIdx.x;
    int w = tid >> 6, l = tid & 63;
    int g = w >> 2, wg = w & 3;
    int tid_g = wg * 64 + l;         // 0..255 within group
    int lrow = l & 15, lhi = l >> 4;

    // carve one 144 KiB LDS block:
    //   [0]      sXm[2]  : 2 x 64x256 bf16 (32 KiB each), 512B rows, swizzled
    //   [65536]  sXmt[2] : 2 x 256x64 bf16 (32 KiB each), 128B rows, swizzled
    //   [131072] sP[8]   : per-wave 16x64 bf16 (2 KiB each), swizzled
    __shared__ __align__(16) char smem[147456];
    char* sXm = smem + g * 32768;
    char* sXmt = smem + 65536 + g * 32768;
    char* sP = smem + 131072 + w * 2048;

    // per-head constants: exp(-d/denom_h) = exp2(d * nc_h)
    float nc[4];
#pragma unroll
    for (int h = 0; h < 4; ++h) {
        float denom = 2.f * expf(2.f * lsig[h]) + 1e-6f;
        nc[h] = -1.44269504f / denom;
    }
    bool uniform = (lsig[0] == lsig[1]) && (lsig[1] == lsig[2]) && (lsig[2] == lsig[3]);

    // Xn A-fragments held in registers for the whole block (same rows per group)
    bf16x8 af[8];
    {
        const u16* xr = xb + ((size_t)(b * Nn + n0 + wg * 16 + lrow)) * Dd;
#pragma unroll
        for (int kt = 0; kt < 8; ++kt) af[kt] = *(const bf16x8*)(xr + kt * 32 + lhi * 8);
    }
    float sqn[4];
#pragma unroll
    for (int r = 0; r < 4; ++r) sqn[r] = sq[b * Nn + n0 + wg * 16 + lhi * 4 + r];

    f32x4 of[16];
#pragma unroll
    for (int dt = 0; dt < 16; ++dt) of[dt] = (f32x4){0.f, 0.f, 0.f, 0.f};

    for (int t = 0; t < 16; ++t) {
        int m0 = (t * 2 + g) * 64;
        __syncthreads();
        // stage Xm tile (64 x 256 bf16) for this group
#pragma unroll
        for (int it = 0; it < 8; ++it) {
            int li = it * 256 + tid_g;
            int row = li >> 5, c16 = li & 31;
            uint4 v = *(const uint4*)(xb + ((size_t)(b * Nn + m0 + row)) * Dd + c16 * 8);
            *(uint4*)(sXm + row * 512 + ((c16 * 16) ^ ((row & 7) << 4))) = v;
        }
        // stage Xm^T tile (256 x 64 bf16) for this group
#pragma unroll
        for (int it = 0; it < 8; ++it) {
            int li = it * 256 + tid_g;
            int drow = li >> 3, c16 = li & 7;
            uint4 v = *(const uint4*)(xbt + ((size_t)(b * Dd + drow)) * Nn + m0 + c16 * 8);
            *(uint4*)(sXmt + drow * 128 + ((c16 * 16) ^ ((drow & 7) << 4))) = v;
        }
        float sqm[4];
#pragma unroll
        for (int jt = 0; jt < 4; ++jt) sqm[jt] = sq[b * Nn + m0 + jt * 16 + lrow];
        __syncthreads();

        // S = Xn . Xm^T   (wave: 16 rows x 64 cols)
        f32x4 sf[4];
#pragma unroll
        for (int jt = 0; jt < 4; ++jt) sf[jt] = (f32x4){0.f, 0.f, 0.f, 0.f};
#pragma unroll
        for (int kt = 0; kt < 8; ++kt) {
#pragma unroll
            for (int jt = 0; jt < 4; ++jt) {
                int row = jt * 16 + lrow;
                bf16x8 bv = *(const bf16x8*)(sXm + row * 512 +
                                             (((kt * 32 + lhi * 8) * 2) ^ ((row & 7) << 4)));
                sf[jt] = __builtin_amdgcn_mfma_f32_16x16x32_bf16(af[kt], bv, sf[jt], 0, 0, 0);
            }
        }

        // P = mean_h exp(-dist * inv_denom_h)  -> per-wave LDS (bf16)
#pragma unroll
        for (int jt = 0; jt < 4; ++jt) {
#pragma unroll
            for (int r = 0; r < 4; ++r) {
                float d = sqn[r] + sqm[jt] - 2.f * sf[jt][r];
                d = fmaxf(d, 0.f);
                float p = exp2f(d * nc[0]);
                if (!uniform)
                    p = 0.25f * (p + exp2f(d * nc[1]) + exp2f(d * nc[2]) + exp2f(d * nc[3]));
                int i = lhi * 4 + r;
                int j = jt * 16 + lrow;
                *(u16*)(sP + i * 128 + ((j * 2) ^ ((i & 7) << 4))) = f2bf(p);
            }
        }

        // O += P . Xm   (same-wave LDS RAW on sP; compiler orders via lgkmcnt)
#pragma unroll
        for (int kt2 = 0; kt2 < 2; ++kt2) {
            bf16x8 pa = *(const bf16x8*)(sP + lrow * 128 +
                                         (((kt2 * 32 + lhi * 8) * 2) ^ ((lrow & 7) << 4)));
#pragma unroll
            for (int dt = 0; dt < 16; ++dt) {
                int row = dt * 16 + lrow;
                bf16x8 bv = *(const bf16x8*)(sXmt + row * 128 +
                                             (((kt2 * 32 + lhi * 8) * 2) ^ ((row & 7) << 4)));
                of[dt] = __builtin_amdgcn_mfma_f32_16x16x32_bf16(pa, bv, of[dt], 0, 0, 0);
            }
        }
    }

    // cross-group reduce (group 1 -> group 0) then write O tile as bf16
    __syncthreads();
    if (g == 1) {
#pragma unroll
        for (int dt = 0; dt < 16; ++dt)
            *(f32x4*)(smem + ((wg * 16 + dt) * 64 + l) * 16) = of[dt];
    }
    __syncthreads();
    if (g == 0) {
#pragma unroll
        for (int dt = 0; dt < 16; ++dt) {
            f32x4 o2 = *(const f32x4*)(smem + ((wg * 16 + dt) * 64 + l) * 16);
            of[dt] += o2;
#pragma unroll
            for (int r = 0; r < 4; ++r) {
                size_t row = (size_t)(b * Nn + n0 + wg * 16 + lhi * 4 + r);
                out1[row * Dd + dt * 16 + lrow] = f2bf(of[dt][r]);
            }
        }
    }
}

// ---------------- projection (out1 @ W^T + b) + ELU + residual + LayerNorm --
// 512 threads = 8 waves: wave (w&3) owns 16 rows, half h=w>>2 owns kc half;
// LDS exchange of the cross-half partial sums, all 8 waves run the epilogue.
__global__ __launch_bounds__(512, 1) void proj_ln_kernel(
    const u16* __restrict__ out1, const u16* __restrict__ Wb,
    const float* __restrict__ x, const float* __restrict__ bvec,
    const float* __restrict__ gamma, const float* __restrict__ beta,
    float* __restrict__ out) {
    int tid = threadIdx.x, w = tid >> 6, l = tid & 63;
    int rg = w & 3, h = w >> 2;
    int lrow = l & 15, lhi = l >> 4;
    size_t row0 = (size_t)blockIdx.x * 64 + rg * 16;

    __shared__ __align__(16) float xch[8 * 16 * 2 * 64];   // 64 KiB

    f32x4 acc[16];
#pragma unroll
    for (int jt = 0; jt < 16; ++jt) acc[jt] = (f32x4){0.f, 0.f, 0.f, 0.f};

#pragma unroll
    for (int kk = 0; kk < 4; ++kk) {
        int kc = h * 4 + kk;
        bf16x8 a = *(const bf16x8*)(out1 + (row0 + lrow) * Dd + kc * 32 + lhi * 8);
#pragma unroll
        for (int jt = 0; jt < 16; ++jt) {
            bf16x8 bv = *(const bf16x8*)(Wb + (size_t)(jt * 16 + lrow) * Dd + kc * 32 + lhi * 8);
            acc[jt] = __builtin_amdgcn_mfma_f32_16x16x32_bf16(a, bv, acc[jt], 0, 0, 0);
        }
    }

    // exchange: write my OTHER-half r values; partner (w^4) wrote my half
#pragma unroll
    for (int jt = 0; jt < 16; ++jt) {
#pragma unroll
        for (int q = 0; q < 2; ++q) {
            int r = (1 - h) * 2 + q;
            xch[(w * 16 + jt) * 128 + q * 64 + l] = acc[jt][r];
        }
    }
    __syncthreads();
#pragma unroll
    for (int jt = 0; jt < 16; ++jt) {
#pragma unroll
        for (int q = 0; q < 2; ++q) {
            acc[jt][h * 2 + q] += xch[((w ^ 4) * 16 + jt) * 128 + q * 64 + l];
        }
    }

#pragma unroll
    for (int q = 0; q < 2; ++q) {
        int r = h * 2 + q;
        size_t grow = row0 + lhi * 4 + r;
        float vbuf[16];
        float s1 = 0.f, s2 = 0.f;
#pragma unroll
        for (int jt = 0; jt < 16; ++jt) {
            int j = jt * 16 + lrow;
            float v = acc[jt][r] + bvec[j];
            float e = v > 0.f ? v : (exp2f(v * 1.44269504f) - 1.f);   // ELU
            float res = e + x[grow * Dd + j];
            vbuf[jt] = res;
            s1 += res;
            s2 += res * res;
        }
#pragma unroll
        for (int m = 1; m < 16; m <<= 1) {
            s1 += __shfl_xor(s1, m);
            s2 += __shfl_xor(s2, m);
        }
        float mean = s1 * (1.f / 256.f);
        float var = s2 * (1.f / 256.f) - mean * mean;
        float rstd = rsqrtf(var + 1e-5f);
#pragma unroll
        for (int jt = 0; jt < 16; ++jt) {
            int j = jt * 16 + lrow;
            out[grow * Dd + j] = (vbuf[jt] - mean) * rstd * gamma[j] + beta[j];
        }
    }
}

// ---------------------------------------------------------------------------
extern "C" void kernel_launch(void* const* d_in, const int* in_sizes, int n_in,
                              void* d_out, int out_size, void* d_ws, size_t ws_size,
                              hipStream_t stream) {
    const float* x = (const float*)d_in[0];
    const float* lsig = (const float*)d_in[1];
    const float* W = (const float*)d_in[2];
    const float* bvec = (const float*)d_in[3];
    const float* gamma = (const float*)d_in[4];
    const float* beta = (const float*)d_in[5];
    float* out = (float*)d_out;

    char* ws = (char*)d_ws;
    u16* xb = (u16*)ws;                                  // 8 MiB
    u16* xbt = (u16*)(ws + 8ull * 1024 * 1024);          // 8 MiB
    u16* o1 = (u16*)(ws + 16ull * 1024 * 1024);          // 8 MiB
    float* sq = (float*)(ws + 24ull * 1024 * 1024);      // 64 KiB
    u16* Wb = (u16*)(ws + 24ull * 1024 * 1024 + 65536);  // 128 KiB

    prep_x_kernel<<<dim3(Bb * Nn / 4), dim3(256), 0, stream>>>(x, xb, sq);
    prep_w_kernel<<<dim3(64), dim3(256), 0, stream>>>(W, Wb);
    prep_t_kernel<<<dim3(Nn / 64, Dd / 64, Bb), dim3(256), 0, stream>>>(xb, xbt);
    fused_adj_kernel<<<dim3(256), dim3(512), 0, stream>>>(xb, xbt, sq, lsig, o1);
    proj_ln_kernel<<<dim3(Bb * Nn / 64), dim3(512), 0, stream>>>(o1, Wb, x, bvec, gamma, beta, out);
}

// Round 3
// 95.374 us; speedup vs baseline: 1.5155x; 1.4427x over previous
//
#include <hip/hip_runtime.h>

typedef unsigned short u16;
typedef __attribute__((ext_vector_type(8))) short bf16x8;   // 8 bf16 = 4 VGPR
typedef __attribute__((ext_vector_type(4))) float f32x4;
typedef __attribute__((ext_vector_type(8))) unsigned short u16x8;

#define DEVI static __device__ __forceinline__

constexpr int Bb = 8, Nn = 2048, Dd = 256;

DEVI u16 f2bf(float f) {
    unsigned int u = __builtin_bit_cast(unsigned int, f);
    u = (u + 0x7fffu + ((u >> 16) & 1u)) >> 16;   // RNE
    return (u16)u;
}
DEVI float bf2f(u16 v) {
    return __builtin_bit_cast(float, (unsigned int)v << 16);
}

// async global->LDS, 16B per lane; lds dest must be wave-uniform base (+lane*16 by HW)
DEVI void gl_lds16(const void* g, void* l) {
    __builtin_amdgcn_global_load_lds(
        (const __attribute__((address_space(1))) unsigned int*)g,
        (__attribute__((address_space(3))) unsigned int*)l, 16, 0, 0);
}

// ---------------- prep: x -> bf16 copy + row sum-of-squares -----------------
__global__ void prep_x_kernel(const float* __restrict__ x, u16* __restrict__ xb,
                              float* __restrict__ sq) {
    int row = blockIdx.x * 4 + (threadIdx.x >> 6);
    int l = threadIdx.x & 63;
    const float4 v = *(const float4*)(x + (size_t)row * Dd + l * 4);
    float ss = v.x * v.x + v.y * v.y + v.z * v.z + v.w * v.w;
    ushort4 o;
    o.x = f2bf(v.x); o.y = f2bf(v.y); o.z = f2bf(v.z); o.w = f2bf(v.w);
    *(ushort4*)(xb + (size_t)row * Dd + l * 4) = o;
#pragma unroll
    for (int s = 1; s < 64; s <<= 1) ss += __shfl_xor(ss, s);
    if (l == 0) sq[row] = ss;
}

// ---------------- prep: W -> bf16 ------------------------------------------
__global__ void prep_w_kernel(const float* __restrict__ W, u16* __restrict__ Wb) {
    int i = (blockIdx.x * 256 + threadIdx.x) * 4;
    const float4 v = *(const float4*)(W + i);
    ushort4 o;
    o.x = f2bf(v.x); o.y = f2bf(v.y); o.z = f2bf(v.z); o.w = f2bf(v.w);
    *(ushort4*)(Wb + i) = o;
}

// ---------------- prep: transpose xb (B,N,D) -> xbt (B,D,N), bf16 ----------
__global__ void prep_t_kernel(const u16* __restrict__ xb, u16* __restrict__ xbt) {
    int nt = blockIdx.x, dt = blockIdx.y, b = blockIdx.z;
    int n0 = nt * 64, d0 = dt * 64;
    __shared__ __align__(16) u16 tile[64 * 64];
    int t = threadIdx.x;
#pragma unroll
    for (int p = 0; p < 2; ++p) {
        int row = p * 32 + (t >> 3);
        int c8 = t & 7;
        uint4 v = *(const uint4*)(xb + ((size_t)(b * Nn + n0 + row)) * Dd + d0 + c8 * 8);
        *(uint4*)((char*)tile + row * 128 + ((c8 * 16) ^ ((row & 7) << 4))) = v;
    }
    __syncthreads();
#pragma unroll
    for (int p = 0; p < 2; ++p) {
        int d = p * 32 + (t >> 3);
        int nn = (t & 7) * 8;
        u16x8 vv;
#pragma unroll
        for (int e = 0; e < 8; ++e) {
            int row = nn + e;
            vv[e] = *(const u16*)((char*)tile + row * 128 + ((d * 2) ^ ((row & 7) << 4)));
        }
        *(u16x8*)(xbt + ((size_t)(b * Dd + d0 + d)) * Nn + n0 + nn) = vv;
    }
}

// ---------------- fused: S^T = Xm.Xn^T, P = mean_h exp(-dist/denom), O += P.Xm
// 512 thr = 8 waves x 32 rows -> BM=256; grid = 64 n-tiles x 4 m-quarters.
// Each block writes a bf16 partial-O for its quarter of the m range.
__global__ __launch_bounds__(512, 1) void fused_adj_kernel(
    const u16* __restrict__ xb, const u16* __restrict__ xbt,
    const float* __restrict__ sq, const float* __restrict__ lsig,
    u16* __restrict__ opart) {
    int bid = blockIdx.x;
    // XCD grouping: 8 blocks sharing (batch b, quarter q) land on one XCD
    int xcd = bid & 7, j = bid >> 3;
    int g = xcd + 8 * (j >> 3);      // 0..31
    int nt8 = j & 7;                 // n-tile within batch
    int b = g >> 2, q = g & 3;
    int r0 = b * Nn + nt8 * 256;     // first n-row (global)
    int m0b = b * Nn + q * 512;      // first m-row of quarter (global)

    int tid = threadIdx.x;
    int w = tid >> 6, l = tid & 63;
    int l15 = l & 15, lhi = l >> 4;

    // LDS 96KB: sXm 64x256 bf16 (512B rows) | sXmt 256x64 bf16 (128B rows) | sP 8 x 32x64 bf16
    __shared__ __align__(16) char smem[98304];
    char* sXm = smem;
    char* sXmt = smem + 32768;
    char* sP = smem + 65536 + w * 4096;

    float nc[4];
#pragma unroll
    for (int h = 0; h < 4; ++h) {
        float denom = 2.f * expf(2.f * lsig[h]) + 1e-6f;
        nc[h] = -1.44269504f / denom;
    }
    bool uniform = (lsig[0] == lsig[1]) && (lsig[1] == lsig[2]) && (lsig[2] == lsig[3]);

    // Xn B-fragments in registers: 2 row-groups x 8 k-tiles
    bf16x8 bf[2][8];
    float sqn[2];
#pragma unroll
    for (int rg = 0; rg < 2; ++rg) {
        const u16* xr = xb + (size_t)(r0 + w * 32 + rg * 16 + l15) * Dd;
#pragma unroll
        for (int kt = 0; kt < 8; ++kt) bf[rg][kt] = *(const bf16x8*)(xr + kt * 32 + lhi * 8);
        sqn[rg] = sq[r0 + w * 32 + rg * 16 + l15];
    }

    f32x4 of[2][16];
#pragma unroll
    for (int rg = 0; rg < 2; ++rg)
#pragma unroll
        for (int dt = 0; dt < 16; ++dt) of[rg][dt] = (f32x4){0.f, 0.f, 0.f, 0.f};

    int swz = (l15 & 7) << 4;        // read-side XOR for 16-row strided reads

    for (int t = 0; t < 8; ++t) {
        int m0 = m0b + t * 64;
        __syncthreads();
        // stage Xm (64x256) via global_load_lds: linear LDS + inverse-swizzled source
#pragma unroll
        for (int it = 0; it < 4; ++it) {
            int c0 = it * 512 + w * 64;          // wave-uniform chunk base
            int c = c0 + l;
            int row = c >> 5, c16 = c & 31;
            gl_lds16(xb + (size_t)(m0 + row) * Dd + (c16 ^ (row & 7)) * 8, sXm + c0 * 16);
        }
        // stage Xm^T (256x64)
#pragma unroll
        for (int it = 0; it < 4; ++it) {
            int c0 = it * 512 + w * 64;
            int c = c0 + l;
            int row = c >> 3, c16 = c & 7;
            gl_lds16(xbt + (size_t)(b * Dd + row) * Nn + (q * 512 + t * 64) + (c16 ^ (row & 7)) * 8,
                     sXmt + c0 * 16);
        }
        __syncthreads();

        // S^T phase: per m-subtile, 8 A-reads feed 16 MFMAs (2 row-groups)
#pragma unroll
        for (int mt = 0; mt < 4; ++mt) {
            float4 sqm = *(const float4*)(sq + m0 + mt * 16 + lhi * 4);
            f32x4 sfv[2];
            sfv[0] = (f32x4){0.f, 0.f, 0.f, 0.f};
            sfv[1] = (f32x4){0.f, 0.f, 0.f, 0.f};
#pragma unroll
            for (int kt = 0; kt < 8; ++kt) {
                bf16x8 av = *(const bf16x8*)(sXm + (mt * 16 + l15) * 512 +
                                             ((kt * 64 + lhi * 16) ^ swz));
                sfv[0] = __builtin_amdgcn_mfma_f32_16x16x32_bf16(av, bf[0][kt], sfv[0], 0, 0, 0);
                sfv[1] = __builtin_amdgcn_mfma_f32_16x16x32_bf16(av, bf[1][kt], sfv[1], 0, 0, 0);
            }
            float sm[4] = {sqm.x, sqm.y, sqm.z, sqm.w};
            // P: lane holds fixed n = rg*16+l15, m = mt*16 + lhi*4 + r  -> packed b64 write
#pragma unroll
            for (int rg = 0; rg < 2; ++rg) {
                ushort4 pk;
#pragma unroll
                for (int r = 0; r < 4; ++r) {
                    float d2 = fmaxf(fmaf(-2.f, sfv[rg][r], sqn[rg] + sm[r]), 0.f);
                    float p = exp2f(d2 * nc[0]);
                    if (!uniform)
                        p = 0.25f * (p + exp2f(d2 * nc[1]) + exp2f(d2 * nc[2]) + exp2f(d2 * nc[3]));
                    ((u16*)&pk)[r] = f2bf(p);
                }
                int n = rg * 16 + l15;
                *(ushort4*)(sP + n * 128 + ((mt * 32 + lhi * 8) ^ ((n & 7) << 4))) = pk;
            }
        }

        // PV phase: O += P . Xm   (same-wave RAW on sP)
#pragma unroll
        for (int kt2 = 0; kt2 < 2; ++kt2) {
            bf16x8 pa0 = *(const bf16x8*)(sP + l15 * 128 + ((kt2 * 64 + lhi * 16) ^ swz));
            bf16x8 pa1 = *(const bf16x8*)(sP + (16 + l15) * 128 + ((kt2 * 64 + lhi * 16) ^ swz));
#pragma unroll
            for (int dt = 0; dt < 16; ++dt) {
                bf16x8 bv = *(const bf16x8*)(sXmt + (dt * 16 + l15) * 128 +
                                             ((kt2 * 64 + lhi * 16) ^ swz));
                of[0][dt] = __builtin_amdgcn_mfma_f32_16x16x32_bf16(pa0, bv, of[0][dt], 0, 0, 0);
                of[1][dt] = __builtin_amdgcn_mfma_f32_16x16x32_bf16(pa1, bv, of[1][dt], 0, 0, 0);
            }
        }
    }

    // write bf16 partial for this m-quarter
    u16* od = opart + (size_t)q * ((size_t)Bb * Nn * Dd);
#pragma unroll
    for (int rg = 0; rg < 2; ++rg)
#pragma unroll
        for (int dt = 0; dt < 16; ++dt)
#pragma unroll
            for (int r = 0; r < 4; ++r) {
                size_t row = (size_t)(r0 + w * 32 + rg * 16 + lhi * 4 + r);
                od[row * Dd + dt * 16 + l15] = f2bf(of[rg][dt][r]);
            }
}

// ---------------- projection (sum(partials) @ W^T + b) + ELU + residual + LN
__global__ __launch_bounds__(512, 1) void proj_ln_kernel(
    const u16* __restrict__ opart, const u16* __restrict__ Wb,
    const float* __restrict__ x, const float* __restrict__ bvec,
    const float* __restrict__ gamma, const float* __restrict__ beta,
    float* __restrict__ out) {
    int tid = threadIdx.x, w = tid >> 6, l = tid & 63;
    int rg = w & 3, h = w >> 2;
    int lrow = l & 15, lhi = l >> 4;
    size_t row0 = (size_t)blockIdx.x * 64 + rg * 16;
    const size_t QS = (size_t)Bb * Nn * Dd;

    __shared__ __align__(16) float xch[8 * 16 * 2 * 64];   // 64 KiB

    f32x4 acc[16];
#pragma unroll
    for (int jt = 0; jt < 16; ++jt) acc[jt] = (f32x4){0.f, 0.f, 0.f, 0.f};

#pragma unroll
    for (int kk = 0; kk < 4; ++kk) {
        int kc = h * 4 + kk;
        float as[8] = {0.f, 0.f, 0.f, 0.f, 0.f, 0.f, 0.f, 0.f};
#pragma unroll
        for (int qq = 0; qq < 4; ++qq) {
            u16x8 v = *(const u16x8*)(opart + QS * qq + (row0 + lrow) * Dd + kc * 32 + lhi * 8);
#pragma unroll
            for (int e = 0; e < 8; ++e) as[e] += bf2f(v[e]);
        }
        bf16x8 a;
#pragma unroll
        for (int e = 0; e < 8; ++e) a[e] = (short)f2bf(as[e]);
#pragma unroll
        for (int jt = 0; jt < 16; ++jt) {
            bf16x8 bv = *(const bf16x8*)(Wb + (size_t)(jt * 16 + lrow) * Dd + kc * 32 + lhi * 8);
            acc[jt] = __builtin_amdgcn_mfma_f32_16x16x32_bf16(a, bv, acc[jt], 0, 0, 0);
        }
    }

    // exchange: write my OTHER-half r values; partner (w^4) wrote my half
#pragma unroll
    for (int jt = 0; jt < 16; ++jt)
#pragma unroll
        for (int qq = 0; qq < 2; ++qq) {
            int r = (1 - h) * 2 + qq;
            xch[(w * 16 + jt) * 128 + qq * 64 + l] = acc[jt][r];
        }
    __syncthreads();
#pragma unroll
    for (int jt = 0; jt < 16; ++jt)
#pragma unroll
        for (int qq = 0; qq < 2; ++qq)
            acc[jt][h * 2 + qq] += xch[((w ^ 4) * 16 + jt) * 128 + qq * 64 + l];

#pragma unroll
    for (int qq = 0; qq < 2; ++qq) {
        int r = h * 2 + qq;
        size_t grow = row0 + lhi * 4 + r;
        float vbuf[16];
        float s1 = 0.f, s2 = 0.f;
#pragma unroll
        for (int jt = 0; jt < 16; ++jt) {
            int jcol = jt * 16 + lrow;
            float v = acc[jt][r] + bvec[jcol];
            float e = v > 0.f ? v : (exp2f(v * 1.44269504f) - 1.f);   // ELU
            float res = e + x[grow * Dd + jcol];
            vbuf[jt] = res;
            s1 += res;
            s2 += res * res;
        }
#pragma unroll
        for (int m = 1; m < 16; m <<= 1) {
            s1 += __shfl_xor(s1, m);
            s2 += __shfl_xor(s2, m);
        }
        float mean = s1 * (1.f / 256.f);
        float var = s2 * (1.f / 256.f) - mean * mean;
        float rstd = rsqrtf(var + 1e-5f);
#pragma unroll
        for (int jt = 0; jt < 16; ++jt) {
            int jcol = jt * 16 + lrow;
            out[grow * Dd + jcol] = (vbuf[jt] - mean) * rstd * gamma[jcol] + beta[jcol];
        }
    }
}

// ---------------------------------------------------------------------------
extern "C" void kernel_launch(void* const* d_in, const int* in_sizes, int n_in,
                              void* d_out, int out_size, void* d_ws, size_t ws_size,
                              hipStream_t stream) {
    const float* x = (const float*)d_in[0];
    const float* lsig = (const float*)d_in[1];
    const float* W = (const float*)d_in[2];
    const float* bvec = (const float*)d_in[3];
    const float* gamma = (const float*)d_in[4];
    const float* beta = (const float*)d_in[5];
    float* out = (float*)d_out;

    char* ws = (char*)d_ws;
    u16* xb = (u16*)ws;                                   // 8 MiB
    u16* xbt = (u16*)(ws + 8388608);                      // 8 MiB
    float* sq = (float*)(ws + 16777216);                  // 64 KiB
    u16* Wb = (u16*)(ws + 16842752);                      // 128 KiB
    u16* opart = (u16*)(ws + 16973824);                   // 4 x 8 MiB bf16 partials

    prep_x_kernel<<<dim3(Bb * Nn / 4), dim3(256), 0, stream>>>(x, xb, sq);
    prep_w_kernel<<<dim3(64), dim3(256), 0, stream>>>(W, Wb);
    prep_t_kernel<<<dim3(Nn / 64, Dd / 64, Bb), dim3(256), 0, stream>>>(xb, xbt);
    fused_adj_kernel<<<dim3(256), dim3(512), 0, stream>>>(xb, xbt, sq, lsig, opart);
    proj_ln_kernel<<<dim3(Bb * Nn / 64), dim3(512), 0, stream>>>(opart, Wb, x, bvec, gamma, beta, out);
}